// Round 9
// baseline (1088.682 us; speedup 1.0000x reference)
//
#include <hip/hip_runtime.h>
#include <math.h>

#define NN 100000
#define NE 1200000
#define EPSV 1e-5f

// binning geometry
#define BUCKET_BITS 9
#define BNODES 512                               // nodes per bucket
#define NBUCK ((NN + BNODES - 1) / BNODES)       // 196
#define NCHUNKS 256
#define CHUNK ((NE + NCHUNKS - 1) / NCHUNKS)     // 4688
#define SCAN_N (NBUCK * NCHUNKS)                 // 50176
#define BUFCAP 8192                              // max edges per bucket (mean 6122)
#define TILE_SHIFT 14                            // src tile = src >> 14 (8 tiles)
#define NKEY 4096                                // 512 dst_local x 8 tiles

__device__ __forceinline__ unsigned short f2bf(float f) {
    unsigned int u = __float_as_uint(f);
    u += 0x7FFF + ((u >> 16) & 1);               // round-to-nearest-even
    return (unsigned short)(u >> 16);
}
__device__ __forceinline__ float bf2f(unsigned short u) {
    return __uint_as_float(((unsigned int)u) << 16);
}

// ---------------- GEMM: Y[n x DOUT](bf16) = X[n x DIN](fp32) @ W[DIN x DOUT] ----------------
// __launch_bounds__(256,4): cap VGPR<=128 so 4 waves/SIMD stay resident
// (uncapped build used 240 VGPR -> 8.9% occupancy -> latency-bound, r8 profile).
template<int DIN, int DOUT, bool BNRELU>
__global__ __launch_bounds__(256, 4)
void gemm_kernel(const float* __restrict__ X, const float* __restrict__ W,
                 unsigned short* __restrict__ Y, int n,
                 const float* __restrict__ scale, const float* __restrict__ shift) {
    constexpr int KC = 64;
    constexpr int NCH = DIN / KC;
    static_assert(DIN % KC == 0, "DIN multiple of 64");
    __shared__ float Xs[64][KC + 4];
    __shared__ float Ws[KC][DOUT + 4];

    const int tid = threadIdx.x;
    const int row0 = blockIdx.x * 64;
    const int tx = tid & 15, ty = tid >> 4;
    const int c0 = tx * 4;
    const int r0 = ty * 4;
    const bool active = (c0 < DOUT);

    float acc[4][4] = {};

    for (int kc = 0; kc < NCH; ++kc) {
        for (int i = tid; i < 64 * (KC / 4); i += 256) {
            int r = i >> 4;
            int c4 = i & 15;
            int gr = row0 + r;
            float4 v = make_float4(0.f, 0.f, 0.f, 0.f);
            if (gr < n)
                v = *(const float4*)&X[(size_t)gr * DIN + kc * KC + c4 * 4];
            if (BNRELU) {
                const float4 sc = *(const float4*)&scale[kc * KC + c4 * 4];
                const float4 sh = *(const float4*)&shift[kc * KC + c4 * 4];
                v.x = fmaxf(v.x * sc.x + sh.x, 0.f);
                v.y = fmaxf(v.y * sc.y + sh.y, 0.f);
                v.z = fmaxf(v.z * sc.z + sh.z, 0.f);
                v.w = fmaxf(v.w * sc.w + sh.w, 0.f);
            }
            *(float4*)&Xs[r][c4 * 4] = v;
        }
        for (int i = tid; i < KC * (DOUT / 4); i += 256) {
            int k = i / (DOUT / 4);
            int c4 = i % (DOUT / 4);
            float4 v = *(const float4*)&W[(size_t)(kc * KC + k) * DOUT + c4 * 4];
            *(float4*)&Ws[k][c4 * 4] = v;
        }
        __syncthreads();

        if (active) {
            for (int k4 = 0; k4 < KC / 4; ++k4) {
                float4 a[4], b[4];
#pragma unroll
                for (int i = 0; i < 4; ++i)
                    a[i] = *(const float4*)&Xs[r0 + i][k4 * 4];
#pragma unroll
                for (int j = 0; j < 4; ++j)
                    b[j] = *(const float4*)&Ws[k4 * 4 + j][c0];
#pragma unroll
                for (int i = 0; i < 4; ++i) {
                    acc[i][0] += a[i].x * b[0].x; acc[i][1] += a[i].x * b[0].y;
                    acc[i][2] += a[i].x * b[0].z; acc[i][3] += a[i].x * b[0].w;
                    acc[i][0] += a[i].y * b[1].x; acc[i][1] += a[i].y * b[1].y;
                    acc[i][2] += a[i].y * b[1].z; acc[i][3] += a[i].y * b[1].w;
                    acc[i][0] += a[i].z * b[2].x; acc[i][1] += a[i].z * b[2].y;
                    acc[i][2] += a[i].z * b[2].z; acc[i][3] += a[i].z * b[2].w;
                    acc[i][0] += a[i].w * b[3].x; acc[i][1] += a[i].w * b[3].y;
                    acc[i][2] += a[i].w * b[3].z; acc[i][3] += a[i].w * b[3].w;
                }
            }
        }
        if (kc + 1 < NCH) __syncthreads();
    }

    if (active) {
#pragma unroll
        for (int i = 0; i < 4; ++i) {
            int gr = row0 + r0 + i;
            if (gr < n) {
                ushort4 o;
                o.x = f2bf(acc[i][0]); o.y = f2bf(acc[i][1]);
                o.z = f2bf(acc[i][2]); o.w = f2bf(acc[i][3]);
                *(ushort4*)&Y[(size_t)gr * DOUT + c0] = o;
            }
        }
    }
}

// ---------------- Pass 1: per-chunk bucket histogram ----------------
__global__ __launch_bounds__(256)
void hist_kernel(const int* __restrict__ dst, int* __restrict__ counts) {
    __shared__ int cnt[NBUCK];
    for (int i = threadIdx.x; i < NBUCK; i += 256) cnt[i] = 0;
    __syncthreads();
    const int base = blockIdx.x * CHUNK;
    const int end = min(base + CHUNK, NE);
    for (int e = base + threadIdx.x; e < end; e += 256)
        atomicAdd(&cnt[dst[e] >> BUCKET_BITS], 1);
    __syncthreads();
    for (int b = threadIdx.x; b < NBUCK; b += 256)
        counts[b * NCHUNKS + blockIdx.x] = cnt[b];
}

// ---------------- generic 3-kernel exclusive scan ----------------
__global__ __launch_bounds__(256)
void block_sums_kernel(const int* __restrict__ v, int* __restrict__ bsums, int n) {
    __shared__ int s[256];
    int i = blockIdx.x * 256 + threadIdx.x;
    s[threadIdx.x] = (i < n) ? v[i] : 0;
    __syncthreads();
    for (int d = 128; d > 0; d >>= 1) {
        if (threadIdx.x < d) s[threadIdx.x] += s[threadIdx.x + d];
        __syncthreads();
    }
    if (threadIdx.x == 0) bsums[blockIdx.x] = s[0];
}

__global__ __launch_bounds__(512)
void scan_bsums_kernel(const int* __restrict__ bsums, int* __restrict__ boff, int nb) {
    __shared__ int s[512];
    int v = (threadIdx.x < nb) ? bsums[threadIdx.x] : 0;
    s[threadIdx.x] = v;
    __syncthreads();
    for (int d = 1; d < 512; d <<= 1) {
        int t = (threadIdx.x >= d) ? s[threadIdx.x - d] : 0;
        __syncthreads();
        s[threadIdx.x] += t;
        __syncthreads();
    }
    if (threadIdx.x < nb) boff[threadIdx.x] = s[threadIdx.x] - v;  // exclusive
}

__global__ __launch_bounds__(256)
void scan_chunks_kernel(const int* __restrict__ v, const int* __restrict__ boff,
                        int* __restrict__ out, int n) {
    __shared__ int s[256];
    int i = blockIdx.x * 256 + threadIdx.x;
    int val = (i < n) ? v[i] : 0;
    s[threadIdx.x] = val;
    __syncthreads();
    for (int d = 1; d < 256; d <<= 1) {
        int t = (threadIdx.x >= d) ? s[threadIdx.x - d] : 0;
        __syncthreads();
        s[threadIdx.x] += t;
        __syncthreads();
    }
    if (i < n) out[i] = boff[blockIdx.x] + s[threadIdx.x] - val;  // exclusive
}

// ---------------- Pass 2: place edges into (bucket,chunk) runs ----------------
// payload: .x = src | (dst_local << 17) as bits, .y = weight
__global__ __launch_bounds__(256)
void place_kernel(const int* __restrict__ src, const int* __restrict__ dst,
                  const float* __restrict__ ew, const int* __restrict__ gofs,
                  float2* __restrict__ binned) {
    __shared__ int lcur[NBUCK];
    for (int i = threadIdx.x; i < NBUCK; i += 256) lcur[i] = 0;
    __syncthreads();
    const int base = blockIdx.x * CHUNK;
    const int end = min(base + CHUNK, NE);
    for (int e = base + threadIdx.x; e < end; e += 256) {
        int d = dst[e];
        int b = d >> BUCKET_BITS;
        int p = gofs[b * NCHUNKS + blockIdx.x] + atomicAdd(&lcur[b], 1);
        float2 pk;
        pk.x = __int_as_float(src[e] | ((d & (BNODES - 1)) << 17));
        pk.y = ew[e];
        binned[p] = pk;
    }
}

// ---------------- Pass 3: per-bucket LDS counting sort by (dst_local, src_tile) ----------------
__global__ __launch_bounds__(256)
void bucket_sort_kernel(const float2* __restrict__ binned, const int* __restrict__ gofs,
                        float2* __restrict__ edges, int* __restrict__ off) {
    __shared__ float2 buf[BUFCAP];
    __shared__ int pos[NKEY];
    __shared__ int psum[256];
    const int tid = threadIdx.x;
    const int b = blockIdx.x;
    const int s = gofs[b * NCHUNKS];
    const int e = (b == NBUCK - 1) ? NE : gofs[(b + 1) * NCHUNKS];
    const int n = e - s;

    for (int i = tid; i < NKEY; i += 256) pos[i] = 0;
    __syncthreads();
    for (int i = tid; i < n; i += 256) {
        int v = __float_as_int(binned[s + i].x);
        int dl = (v >> 17) & (BNODES - 1);
        int t = (v & 0x1FFFF) >> TILE_SHIFT;
        atomicAdd(&pos[(dl << 3) | t], 1);
    }
    __syncthreads();
    // exclusive scan of pos[4096]: 16 sequential per thread + 256-scan
    const int base = tid * 16;
    int run = 0;
#pragma unroll
    for (int i = 0; i < 16; ++i) { int c = pos[base + i]; pos[base + i] = run; run += c; }
    psum[tid] = run;
    __syncthreads();
    for (int d = 1; d < 256; d <<= 1) {
        int t = (tid >= d) ? psum[tid - d] : 0;
        __syncthreads();
        psum[tid] += t;
        __syncthreads();
    }
    const int chunk_off = psum[tid] - run;   // exclusive across chunks
#pragma unroll
    for (int i = 0; i < 16; ++i) pos[base + i] += chunk_off;
    __syncthreads();
    // node offsets = first key of each dst_local (before pos is consumed as cursor)
    const int node0 = b * BNODES;
    for (int i = tid; i < BNODES; i += 256) {
        int node = node0 + i;
        if (node < NN) off[node] = s + pos[i << 3];
    }
    if (b == NBUCK - 1 && tid == 0) off[NN] = NE;
    __syncthreads();
    // scatter into LDS by key
    for (int i = tid; i < n; i += 256) {
        float2 pk = binned[s + i];
        int v = __float_as_int(pk.x);
        int dl = (v >> 17) & (BNODES - 1);
        int t = (v & 0x1FFFF) >> TILE_SHIFT;
        int p = atomicAdd(&pos[(dl << 3) | t], 1);
        pk.x = __int_as_float(v & 0x1FFFF);  // strip dst_local
        if (p < BUFCAP) buf[p] = pk;
    }
    __syncthreads();
    const int m = (n < BUFCAP) ? n : BUFCAP;
    for (int i = tid; i < m; i += 256)
        edges[s + i] = buf[i];
}

// ---------------- Aggregation: y[v] = sum_j w_j * bf2f(h[src_j]) (+bias), fp32 out ----------------
// One node per 32-lane half-wave (lane loads uint = 2 bf16 features).
// 8 nodes per 256-thread block; 2 independent gather streams per wave.
template<int D, bool BIAS>
__global__ __launch_bounds__(256)
void agg_kernel(const unsigned short* __restrict__ h, const float2* __restrict__ edges,
                const int* __restrict__ off, float* __restrict__ y,
                const float* __restrict__ bias) {
    constexpr int NU = D / 2;                    // uints per row
    const unsigned int* __restrict__ h32 = (const unsigned int*)h;
    const int fl = threadIdx.x & 31;             // uint index within row
    const int v = blockIdx.x * 8 + (threadIdx.x >> 5);
    if (v >= NN) return;
    const bool act = (fl < NU);
    const int s = off[v], e = off[v + 1];
    float a0 = 0.f, a1 = 0.f, b0 = 0.f, b1 = 0.f;
    float c0 = 0.f, c1 = 0.f, d0 = 0.f, d1 = 0.f;
    int j = s;
    if (act) {
        for (; j + 7 < e; j += 8) {
            float2 p0 = edges[j + 0], p1 = edges[j + 1], p2 = edges[j + 2], p3 = edges[j + 3];
            float2 p4 = edges[j + 4], p5 = edges[j + 5], p6 = edges[j + 6], p7 = edges[j + 7];
            unsigned int h0 = h32[(size_t)__float_as_int(p0.x) * NU + fl];
            unsigned int h1 = h32[(size_t)__float_as_int(p1.x) * NU + fl];
            unsigned int h2 = h32[(size_t)__float_as_int(p2.x) * NU + fl];
            unsigned int h3 = h32[(size_t)__float_as_int(p3.x) * NU + fl];
            unsigned int h4 = h32[(size_t)__float_as_int(p4.x) * NU + fl];
            unsigned int h5 = h32[(size_t)__float_as_int(p5.x) * NU + fl];
            unsigned int h6 = h32[(size_t)__float_as_int(p6.x) * NU + fl];
            unsigned int h7 = h32[(size_t)__float_as_int(p7.x) * NU + fl];
            a0 += bf2f((unsigned short)h0) * p0.y + bf2f((unsigned short)h1) * p1.y;
            a1 += bf2f((unsigned short)(h0 >> 16)) * p0.y + bf2f((unsigned short)(h1 >> 16)) * p1.y;
            b0 += bf2f((unsigned short)h2) * p2.y + bf2f((unsigned short)h3) * p3.y;
            b1 += bf2f((unsigned short)(h2 >> 16)) * p2.y + bf2f((unsigned short)(h3 >> 16)) * p3.y;
            c0 += bf2f((unsigned short)h4) * p4.y + bf2f((unsigned short)h5) * p5.y;
            c1 += bf2f((unsigned short)(h4 >> 16)) * p4.y + bf2f((unsigned short)(h5 >> 16)) * p5.y;
            d0 += bf2f((unsigned short)h6) * p6.y + bf2f((unsigned short)h7) * p7.y;
            d1 += bf2f((unsigned short)(h6 >> 16)) * p6.y + bf2f((unsigned short)(h7 >> 16)) * p7.y;
        }
        for (; j + 3 < e; j += 4) {
            float2 p0 = edges[j + 0], p1 = edges[j + 1], p2 = edges[j + 2], p3 = edges[j + 3];
            unsigned int h0 = h32[(size_t)__float_as_int(p0.x) * NU + fl];
            unsigned int h1 = h32[(size_t)__float_as_int(p1.x) * NU + fl];
            unsigned int h2 = h32[(size_t)__float_as_int(p2.x) * NU + fl];
            unsigned int h3 = h32[(size_t)__float_as_int(p3.x) * NU + fl];
            a0 += bf2f((unsigned short)h0) * p0.y + bf2f((unsigned short)h1) * p1.y;
            a1 += bf2f((unsigned short)(h0 >> 16)) * p0.y + bf2f((unsigned short)(h1 >> 16)) * p1.y;
            b0 += bf2f((unsigned short)h2) * p2.y + bf2f((unsigned short)h3) * p3.y;
            b1 += bf2f((unsigned short)(h2 >> 16)) * p2.y + bf2f((unsigned short)(h3 >> 16)) * p3.y;
        }
        for (; j < e; ++j) {
            float2 p0 = edges[j];
            unsigned int h0 = h32[(size_t)__float_as_int(p0.x) * NU + fl];
            c0 += bf2f((unsigned short)h0) * p0.y;
            c1 += bf2f((unsigned short)(h0 >> 16)) * p0.y;
        }
        float r0 = (a0 + b0) + (c0 + d0);
        float r1 = (a1 + b1) + (c1 + d1);
        if (BIAS) { r0 += bias[2 * fl]; r1 += bias[2 * fl + 1]; }
        *(float2*)&y[(size_t)v * D + 2 * fl] = make_float2(r0, r1);
    }
}

// ---------------- BN stats: stats[0..63]=sum, stats[64..127]=sumsq ----------------
__global__ __launch_bounds__(256)
void bn_stats_kernel(const float* __restrict__ x, float* __restrict__ stats, int n) {
    __shared__ float s_sum[256];
    __shared__ float s_sq[256];
    const int tid = threadIdx.x;
    const int c = tid & 63;
    const int rg = tid >> 6;
    float sum = 0.f, sq = 0.f;
    for (int r = blockIdx.x * 4 + rg; r < n; r += gridDim.x * 4) {
        float v = x[(size_t)r * 64 + c];
        sum += v;
        sq += v * v;
    }
    s_sum[tid] = sum;
    s_sq[tid] = sq;
    __syncthreads();
    if (tid < 64) {
        float ts = s_sum[tid] + s_sum[tid + 64] + s_sum[tid + 128] + s_sum[tid + 192];
        float tq = s_sq[tid] + s_sq[tid + 64] + s_sq[tid + 128] + s_sq[tid + 192];
        atomicAdd(&stats[tid], ts);
        atomicAdd(&stats[64 + tid], tq);
    }
}

// ---------------- finalize BN ----------------
__global__ __launch_bounds__(64)
void bn_final_kernel(const float* __restrict__ stats, const float* __restrict__ g,
                     const float* __restrict__ beta, float* __restrict__ scale,
                     float* __restrict__ shift) {
    int c = threadIdx.x;
    float mu = stats[c] * (1.f / NN);
    float var = stats[64 + c] * (1.f / NN) - mu * mu;
    float rs = rsqrtf(var + EPSV);
    float sc = g[c] * rs;
    scale[c] = sc;
    shift[c] = beta[c] - mu * sc;
}

extern "C" void kernel_launch(void* const* d_in, const int* in_sizes, int n_in,
                              void* d_out, int out_size, void* d_ws, size_t ws_size,
                              hipStream_t stream) {
    const float* nf    = (const float*)d_in[0];
    const int*   ei    = (const int*)d_in[1];   // [2][E]
    const float* ew    = (const float*)d_in[2];
    const float* W1    = (const float*)d_in[3];
    // b1 (d_in[4]) cancels inside BN
    const float* g1    = (const float*)d_in[5];
    const float* beta1 = (const float*)d_in[6];
    const float* W2    = (const float*)d_in[7];
    // b2 (d_in[8]) cancels inside BN
    const float* g2    = (const float*)d_in[9];
    const float* beta2 = (const float*)d_in[10];
    const float* W3    = (const float*)d_in[11];
    const float* b3    = (const float*)d_in[12];

    const int* src = ei;
    const int* dst = ei + NE;

    // workspace layout (4B units)
    unsigned short* hbuf = (unsigned short*)d_ws;       // NN*64 bf16 (12.8MB); binned aliases it
    float*  aggbuf = (float*)(hbuf + (size_t)NN * 64);  // NN*64 fp32
    float2* edges  = (float2*)(aggbuf + (size_t)NN * 64); // NE float2
    int*    off    = (int*)(edges + NE);                // NN+1
    int*    counts = off + NN + 1;                      // SCAN_N
    int*    gofs   = counts + SCAN_N;                   // SCAN_N
    int*    bsums  = gofs + SCAN_N;                     // 512
    int*    boff   = bsums + 512;                       // 512
    float*  stats  = (float*)(boff + 512);              // 128
    float*  scale  = stats + 128;                       // 64
    float*  shift  = scale + 64;                        // 64

    float2* binned = (float2*)hbuf;                     // scratch, consumed before gemm1

    float* out = (float*)d_out;

    const int SB = (SCAN_N + 255) / 256;   // 196
    const int ggrid = (NN + 63) / 64;      // 1563
    const int agrid = (NN + 7) / 8;        // 12500

    // ---------- CSR build: hist -> scan -> place -> bucket sort ----------
    hist_kernel<<<NCHUNKS, 256, 0, stream>>>(dst, counts);
    block_sums_kernel<<<SB, 256, 0, stream>>>(counts, bsums, SCAN_N);
    scan_bsums_kernel<<<1, 512, 0, stream>>>(bsums, boff, SB);
    scan_chunks_kernel<<<SB, 256, 0, stream>>>(counts, boff, gofs, SCAN_N);
    place_kernel<<<NCHUNKS, 256, 0, stream>>>(src, dst, ew, gofs, binned);
    bucket_sort_kernel<<<NBUCK, 256, 0, stream>>>(binned, gofs, edges, off);

    // ---------- layer 1: GCNConv(128->64) ----------
    gemm_kernel<128, 64, false><<<ggrid, 256, 0, stream>>>(nf, W1, hbuf, NN, nullptr, nullptr);
    agg_kernel<64, false><<<agrid, 256, 0, stream>>>(hbuf, edges, off, aggbuf, nullptr);
    (void)hipMemsetAsync(stats, 0, 128 * sizeof(float), stream);
    bn_stats_kernel<<<512, 256, 0, stream>>>(aggbuf, stats, NN);
    bn_final_kernel<<<1, 64, 0, stream>>>(stats, g1, beta1, scale, shift);

    // ---------- layer 2: (BN+ReLU fused into GEMM load) GCNConv(64->64) ----------
    gemm_kernel<64, 64, true><<<ggrid, 256, 0, stream>>>(aggbuf, W2, hbuf, NN, scale, shift);
    agg_kernel<64, false><<<agrid, 256, 0, stream>>>(hbuf, edges, off, aggbuf, nullptr);
    (void)hipMemsetAsync(stats, 0, 128 * sizeof(float), stream);
    bn_stats_kernel<<<512, 256, 0, stream>>>(aggbuf, stats, NN);
    bn_final_kernel<<<1, 64, 0, stream>>>(stats, g2, beta2, scale, shift);

    // ---------- layer 3: (BN+ReLU fused) GCNConv(64->40) + b3 ----------
    gemm_kernel<64, 40, true><<<ggrid, 256, 0, stream>>>(aggbuf, W3, hbuf, NN, scale, shift);
    agg_kernel<40, true><<<agrid, 256, 0, stream>>>(hbuf, edges, off, out, b3);
}

// Round 10
// 263.868 us; speedup vs baseline: 4.1259x; 4.1259x over previous
//
#include <hip/hip_runtime.h>
#include <math.h>

#define NN 100000
#define NE 1200000
#define EPSV 1e-5f

// binning geometry
#define BUCKET_BITS 9
#define BNODES 512                               // nodes per bucket
#define NBUCK ((NN + BNODES - 1) / BNODES)       // 196
#define NCHUNKS 256
#define CHUNK ((NE + NCHUNKS - 1) / NCHUNKS)     // 4688
#define SCAN_N (NBUCK * NCHUNKS)                 // 50176
#define BUFCAP 8192                              // max edges per bucket (mean 6122)
#define TILE_SHIFT 14                            // src tile = src >> 14 (8 tiles)
#define NKEY 4096                                // 512 dst_local x 8 tiles

typedef __attribute__((ext_vector_type(8))) short short8;
typedef __attribute__((ext_vector_type(4))) float f32x4;

__device__ __forceinline__ unsigned short f2bf(float f) {
    unsigned int u = __float_as_uint(f);
    u += 0x7FFF + ((u >> 16) & 1);               // round-to-nearest-even
    return (unsigned short)(u >> 16);
}
__device__ __forceinline__ float bf2f(unsigned short u) {
    return __uint_as_float(((unsigned int)u) << 16);
}

// ---------------- MFMA GEMM: Y[n x DOUT](bf16) = X[n x DIN](fp32) @ W[DIN x DOUT](fp32) ----------------
// 256 threads = 4 waves; 64 rows/block; wave w owns rows w*16..+15, all DOUT cols.
// X and W^T staged in LDS as bf16 with +8 pad (row stride % 32 dwords == 4 -> 2-way alias, free).
// mfma_f32_16x16x32_bf16 fragments (m89-verified):
//   A: lane holds X[w*16 + (lane&15)][kb + (lane>>4)*8 + j], j=0..7   (ds_read_b128)
//   B: lane holds W[kb + (lane>>4)*8 + j][nf*16 + (lane&15)]          (from Wt, contiguous)
//   D: row = (lane>>4)*4 + j, col = lane&15
template<int DIN, int DOUT, int NF, bool BNRELU>
__global__ __launch_bounds__(256)
void gemm_mfma_kernel(const float* __restrict__ X, const float* __restrict__ W,
                      unsigned short* __restrict__ Y, int n,
                      const float* __restrict__ scale, const float* __restrict__ shift) {
    constexpr int LD = DIN + 8;                  // bf16 units; 136 or 72 -> stride%32dw == 4
    constexpr int DP = NF * 16;                  // padded col count
    static_assert(DIN % 32 == 0, "K multiple of 32");
    __shared__ unsigned short Xs[64][LD];
    __shared__ unsigned short Wt[DP][LD];

    const int tid = threadIdx.x;
    const int row0 = blockIdx.x * 64;

    // ---- stage X tile (fp32 -> optional BN+ReLU -> bf16) ----
    for (int i = tid; i < 64 * (DIN / 4); i += 256) {
        int r = i / (DIN / 4);
        int c4 = i % (DIN / 4);
        int gr = row0 + r;
        float4 v = make_float4(0.f, 0.f, 0.f, 0.f);
        if (gr < n)
            v = *(const float4*)&X[(size_t)gr * DIN + c4 * 4];
        if (BNRELU) {
            const float4 sc = *(const float4*)&scale[c4 * 4];
            const float4 sh = *(const float4*)&shift[c4 * 4];
            v.x = fmaxf(v.x * sc.x + sh.x, 0.f);
            v.y = fmaxf(v.y * sc.y + sh.y, 0.f);
            v.z = fmaxf(v.z * sc.z + sh.z, 0.f);
            v.w = fmaxf(v.w * sc.w + sh.w, 0.f);
        }
        ushort4 o;
        o.x = f2bf(v.x); o.y = f2bf(v.y); o.z = f2bf(v.z); o.w = f2bf(v.w);
        *(ushort4*)&Xs[r][c4 * 4] = o;
    }
    // ---- stage W transposed (fp32 -> bf16), zero-pad cols >= DOUT ----
    for (int i = tid; i < DIN * DOUT; i += 256) {
        int k = i / DOUT;
        int c = i - k * DOUT;
        Wt[c][k] = f2bf(W[i]);
    }
    if (DP > DOUT) {
        for (int i = tid; i < DIN * (DP - DOUT); i += 256) {
            int k = i / (DP - DOUT);
            int c = DOUT + (i - k * (DP - DOUT));
            Wt[c][k] = 0;
        }
    }
    __syncthreads();

    const int w = tid >> 6;
    const int lane = tid & 63;
    const int lr = lane & 15;
    const int kg = lane >> 4;

    f32x4 acc[NF];
#pragma unroll
    for (int nf = 0; nf < NF; ++nf) acc[nf] = (f32x4){0.f, 0.f, 0.f, 0.f};

#pragma unroll
    for (int t = 0; t < DIN / 32; ++t) {
        const int kb = t * 32 + kg * 8;
        short8 a = *(const short8*)&Xs[w * 16 + lr][kb];
#pragma unroll
        for (int nf = 0; nf < NF; ++nf) {
            short8 b = *(const short8*)&Wt[nf * 16 + lr][kb];
            acc[nf] = __builtin_amdgcn_mfma_f32_16x16x32_bf16(a, b, acc[nf], 0, 0, 0);
        }
    }

    // ---- C write: row=(kg*4+j), col=nf*16+lr ----
#pragma unroll
    for (int nf = 0; nf < NF; ++nf) {
        const int c = nf * 16 + lr;
        if (c < DOUT) {
#pragma unroll
            for (int j = 0; j < 4; ++j) {
                int gr = row0 + w * 16 + kg * 4 + j;
                if (gr < n)
                    Y[(size_t)gr * DOUT + c] = f2bf(acc[nf][j]);
            }
        }
    }
}

// ---------------- Pass 1: per-chunk bucket histogram ----------------
__global__ __launch_bounds__(256)
void hist_kernel(const int* __restrict__ dst, int* __restrict__ counts) {
    __shared__ int cnt[NBUCK];
    for (int i = threadIdx.x; i < NBUCK; i += 256) cnt[i] = 0;
    __syncthreads();
    const int base = blockIdx.x * CHUNK;
    const int end = min(base + CHUNK, NE);
    for (int e = base + threadIdx.x; e < end; e += 256)
        atomicAdd(&cnt[dst[e] >> BUCKET_BITS], 1);
    __syncthreads();
    for (int b = threadIdx.x; b < NBUCK; b += 256)
        counts[b * NCHUNKS + blockIdx.x] = cnt[b];
}

// ---------------- generic 3-kernel exclusive scan ----------------
__global__ __launch_bounds__(256)
void block_sums_kernel(const int* __restrict__ v, int* __restrict__ bsums, int n) {
    __shared__ int s[256];
    int i = blockIdx.x * 256 + threadIdx.x;
    s[threadIdx.x] = (i < n) ? v[i] : 0;
    __syncthreads();
    for (int d = 128; d > 0; d >>= 1) {
        if (threadIdx.x < d) s[threadIdx.x] += s[threadIdx.x + d];
        __syncthreads();
    }
    if (threadIdx.x == 0) bsums[blockIdx.x] = s[0];
}

__global__ __launch_bounds__(512)
void scan_bsums_kernel(const int* __restrict__ bsums, int* __restrict__ boff, int nb) {
    __shared__ int s[512];
    int v = (threadIdx.x < nb) ? bsums[threadIdx.x] : 0;
    s[threadIdx.x] = v;
    __syncthreads();
    for (int d = 1; d < 512; d <<= 1) {
        int t = (threadIdx.x >= d) ? s[threadIdx.x - d] : 0;
        __syncthreads();
        s[threadIdx.x] += t;
        __syncthreads();
    }
    if (threadIdx.x < nb) boff[threadIdx.x] = s[threadIdx.x] - v;  // exclusive
}

__global__ __launch_bounds__(256)
void scan_chunks_kernel(const int* __restrict__ v, const int* __restrict__ boff,
                        int* __restrict__ out, int n) {
    __shared__ int s[256];
    int i = blockIdx.x * 256 + threadIdx.x;
    int val = (i < n) ? v[i] : 0;
    s[threadIdx.x] = val;
    __syncthreads();
    for (int d = 1; d < 256; d <<= 1) {
        int t = (threadIdx.x >= d) ? s[threadIdx.x - d] : 0;
        __syncthreads();
        s[threadIdx.x] += t;
        __syncthreads();
    }
    if (i < n) out[i] = boff[blockIdx.x] + s[threadIdx.x] - val;  // exclusive
}

// ---------------- Pass 2: place edges into (bucket,chunk) runs ----------------
// payload: .x = src | (dst_local << 17) as bits, .y = weight
__global__ __launch_bounds__(256)
void place_kernel(const int* __restrict__ src, const int* __restrict__ dst,
                  const float* __restrict__ ew, const int* __restrict__ gofs,
                  float2* __restrict__ binned) {
    __shared__ int lcur[NBUCK];
    for (int i = threadIdx.x; i < NBUCK; i += 256) lcur[i] = 0;
    __syncthreads();
    const int base = blockIdx.x * CHUNK;
    const int end = min(base + CHUNK, NE);
    for (int e = base + threadIdx.x; e < end; e += 256) {
        int d = dst[e];
        int b = d >> BUCKET_BITS;
        int p = gofs[b * NCHUNKS + blockIdx.x] + atomicAdd(&lcur[b], 1);
        float2 pk;
        pk.x = __int_as_float(src[e] | ((d & (BNODES - 1)) << 17));
        pk.y = ew[e];
        binned[p] = pk;
    }
}

// ---------------- Pass 3: per-bucket LDS counting sort by (dst_local, src_tile) ----------------
__global__ __launch_bounds__(256)
void bucket_sort_kernel(const float2* __restrict__ binned, const int* __restrict__ gofs,
                        float2* __restrict__ edges, int* __restrict__ off) {
    __shared__ float2 buf[BUFCAP];
    __shared__ int pos[NKEY];
    __shared__ int psum[256];
    const int tid = threadIdx.x;
    const int b = blockIdx.x;
    const int s = gofs[b * NCHUNKS];
    const int e = (b == NBUCK - 1) ? NE : gofs[(b + 1) * NCHUNKS];
    const int n = e - s;

    for (int i = tid; i < NKEY; i += 256) pos[i] = 0;
    __syncthreads();
    for (int i = tid; i < n; i += 256) {
        int v = __float_as_int(binned[s + i].x);
        int dl = (v >> 17) & (BNODES - 1);
        int t = (v & 0x1FFFF) >> TILE_SHIFT;
        atomicAdd(&pos[(dl << 3) | t], 1);
    }
    __syncthreads();
    // exclusive scan of pos[4096]: 16 sequential per thread + 256-scan
    const int base = tid * 16;
    int run = 0;
#pragma unroll
    for (int i = 0; i < 16; ++i) { int c = pos[base + i]; pos[base + i] = run; run += c; }
    psum[tid] = run;
    __syncthreads();
    for (int d = 1; d < 256; d <<= 1) {
        int t = (tid >= d) ? psum[tid - d] : 0;
        __syncthreads();
        psum[tid] += t;
        __syncthreads();
    }
    const int chunk_off = psum[tid] - run;   // exclusive across chunks
#pragma unroll
    for (int i = 0; i < 16; ++i) pos[base + i] += chunk_off;
    __syncthreads();
    // node offsets = first key of each dst_local (before pos is consumed as cursor)
    const int node0 = b * BNODES;
    for (int i = tid; i < BNODES; i += 256) {
        int node = node0 + i;
        if (node < NN) off[node] = s + pos[i << 3];
    }
    if (b == NBUCK - 1 && tid == 0) off[NN] = NE;
    __syncthreads();
    // scatter into LDS by key
    for (int i = tid; i < n; i += 256) {
        float2 pk = binned[s + i];
        int v = __float_as_int(pk.x);
        int dl = (v >> 17) & (BNODES - 1);
        int t = (v & 0x1FFFF) >> TILE_SHIFT;
        int p = atomicAdd(&pos[(dl << 3) | t], 1);
        pk.x = __int_as_float(v & 0x1FFFF);  // strip dst_local
        if (p < BUFCAP) buf[p] = pk;
    }
    __syncthreads();
    const int m = (n < BUFCAP) ? n : BUFCAP;
    for (int i = tid; i < m; i += 256)
        edges[s + i] = buf[i];
}

// ---------------- Aggregation: y[v] = sum_j w_j * bf2f(h[src_j]) (+bias), fp32 out ----------------
// One node per 32-lane half-wave (lane loads uint = 2 bf16 features).
// 8 nodes per 256-thread block; 2 independent gather streams per wave.
template<int D, bool BIAS>
__global__ __launch_bounds__(256)
void agg_kernel(const unsigned short* __restrict__ h, const float2* __restrict__ edges,
                const int* __restrict__ off, float* __restrict__ y,
                const float* __restrict__ bias) {
    constexpr int NU = D / 2;                    // uints per row
    const unsigned int* __restrict__ h32 = (const unsigned int*)h;
    const int fl = threadIdx.x & 31;             // uint index within row
    const int v = blockIdx.x * 8 + (threadIdx.x >> 5);
    if (v >= NN) return;
    const bool act = (fl < NU);
    const int s = off[v], e = off[v + 1];
    float a0 = 0.f, a1 = 0.f, b0 = 0.f, b1 = 0.f;
    float c0 = 0.f, c1 = 0.f, d0 = 0.f, d1 = 0.f;
    int j = s;
    if (act) {
        for (; j + 7 < e; j += 8) {
            float2 p0 = edges[j + 0], p1 = edges[j + 1], p2 = edges[j + 2], p3 = edges[j + 3];
            float2 p4 = edges[j + 4], p5 = edges[j + 5], p6 = edges[j + 6], p7 = edges[j + 7];
            unsigned int h0 = h32[(size_t)__float_as_int(p0.x) * NU + fl];
            unsigned int h1 = h32[(size_t)__float_as_int(p1.x) * NU + fl];
            unsigned int h2 = h32[(size_t)__float_as_int(p2.x) * NU + fl];
            unsigned int h3 = h32[(size_t)__float_as_int(p3.x) * NU + fl];
            unsigned int h4 = h32[(size_t)__float_as_int(p4.x) * NU + fl];
            unsigned int h5 = h32[(size_t)__float_as_int(p5.x) * NU + fl];
            unsigned int h6 = h32[(size_t)__float_as_int(p6.x) * NU + fl];
            unsigned int h7 = h32[(size_t)__float_as_int(p7.x) * NU + fl];
            a0 += bf2f((unsigned short)h0) * p0.y + bf2f((unsigned short)h1) * p1.y;
            a1 += bf2f((unsigned short)(h0 >> 16)) * p0.y + bf2f((unsigned short)(h1 >> 16)) * p1.y;
            b0 += bf2f((unsigned short)h2) * p2.y + bf2f((unsigned short)h3) * p3.y;
            b1 += bf2f((unsigned short)(h2 >> 16)) * p2.y + bf2f((unsigned short)(h3 >> 16)) * p3.y;
            c0 += bf2f((unsigned short)h4) * p4.y + bf2f((unsigned short)h5) * p5.y;
            c1 += bf2f((unsigned short)(h4 >> 16)) * p4.y + bf2f((unsigned short)(h5 >> 16)) * p5.y;
            d0 += bf2f((unsigned short)h6) * p6.y + bf2f((unsigned short)h7) * p7.y;
            d1 += bf2f((unsigned short)(h6 >> 16)) * p6.y + bf2f((unsigned short)(h7 >> 16)) * p7.y;
        }
        for (; j + 3 < e; j += 4) {
            float2 p0 = edges[j + 0], p1 = edges[j + 1], p2 = edges[j + 2], p3 = edges[j + 3];
            unsigned int h0 = h32[(size_t)__float_as_int(p0.x) * NU + fl];
            unsigned int h1 = h32[(size_t)__float_as_int(p1.x) * NU + fl];
            unsigned int h2 = h32[(size_t)__float_as_int(p2.x) * NU + fl];
            unsigned int h3 = h32[(size_t)__float_as_int(p3.x) * NU + fl];
            a0 += bf2f((unsigned short)h0) * p0.y + bf2f((unsigned short)h1) * p1.y;
            a1 += bf2f((unsigned short)(h0 >> 16)) * p0.y + bf2f((unsigned short)(h1 >> 16)) * p1.y;
            b0 += bf2f((unsigned short)h2) * p2.y + bf2f((unsigned short)h3) * p3.y;
            b1 += bf2f((unsigned short)(h2 >> 16)) * p2.y + bf2f((unsigned short)(h3 >> 16)) * p3.y;
        }
        for (; j < e; ++j) {
            float2 p0 = edges[j];
            unsigned int h0 = h32[(size_t)__float_as_int(p0.x) * NU + fl];
            c0 += bf2f((unsigned short)h0) * p0.y;
            c1 += bf2f((unsigned short)(h0 >> 16)) * p0.y;
        }
        float r0 = (a0 + b0) + (c0 + d0);
        float r1 = (a1 + b1) + (c1 + d1);
        if (BIAS) { r0 += bias[2 * fl]; r1 += bias[2 * fl + 1]; }
        *(float2*)&y[(size_t)v * D + 2 * fl] = make_float2(r0, r1);
    }
}

// ---------------- BN stats: stats[0..63]=sum, stats[64..127]=sumsq ----------------
__global__ __launch_bounds__(256)
void bn_stats_kernel(const float* __restrict__ x, float* __restrict__ stats, int n) {
    __shared__ float s_sum[256];
    __shared__ float s_sq[256];
    const int tid = threadIdx.x;
    const int c = tid & 63;
    const int rg = tid >> 6;
    float sum = 0.f, sq = 0.f;
    for (int r = blockIdx.x * 4 + rg; r < n; r += gridDim.x * 4) {
        float v = x[(size_t)r * 64 + c];
        sum += v;
        sq += v * v;
    }
    s_sum[tid] = sum;
    s_sq[tid] = sq;
    __syncthreads();
    if (tid < 64) {
        float ts = s_sum[tid] + s_sum[tid + 64] + s_sum[tid + 128] + s_sum[tid + 192];
        float tq = s_sq[tid] + s_sq[tid + 64] + s_sq[tid + 128] + s_sq[tid + 192];
        atomicAdd(&stats[tid], ts);
        atomicAdd(&stats[64 + tid], tq);
    }
}

// ---------------- finalize BN ----------------
__global__ __launch_bounds__(64)
void bn_final_kernel(const float* __restrict__ stats, const float* __restrict__ g,
                     const float* __restrict__ beta, float* __restrict__ scale,
                     float* __restrict__ shift) {
    int c = threadIdx.x;
    float mu = stats[c] * (1.f / NN);
    float var = stats[64 + c] * (1.f / NN) - mu * mu;
    float rs = rsqrtf(var + EPSV);
    float sc = g[c] * rs;
    scale[c] = sc;
    shift[c] = beta[c] - mu * sc;
}

extern "C" void kernel_launch(void* const* d_in, const int* in_sizes, int n_in,
                              void* d_out, int out_size, void* d_ws, size_t ws_size,
                              hipStream_t stream) {
    const float* nf    = (const float*)d_in[0];
    const int*   ei    = (const int*)d_in[1];   // [2][E]
    const float* ew    = (const float*)d_in[2];
    const float* W1    = (const float*)d_in[3];
    // b1 (d_in[4]) cancels inside BN
    const float* g1    = (const float*)d_in[5];
    const float* beta1 = (const float*)d_in[6];
    const float* W2    = (const float*)d_in[7];
    // b2 (d_in[8]) cancels inside BN
    const float* g2    = (const float*)d_in[9];
    const float* beta2 = (const float*)d_in[10];
    const float* W3    = (const float*)d_in[11];
    const float* b3    = (const float*)d_in[12];

    const int* src = ei;
    const int* dst = ei + NE;

    // workspace layout (4B units)
    unsigned short* hbuf = (unsigned short*)d_ws;       // NN*64 bf16 (12.8MB); binned aliases it
    float*  aggbuf = (float*)(hbuf + (size_t)NN * 64);  // NN*64 fp32
    float2* edges  = (float2*)(aggbuf + (size_t)NN * 64); // NE float2
    int*    off    = (int*)(edges + NE);                // NN+1
    int*    counts = off + NN + 1;                      // SCAN_N
    int*    gofs   = counts + SCAN_N;                   // SCAN_N
    int*    bsums  = gofs + SCAN_N;                     // 512
    int*    boff   = bsums + 512;                       // 512
    float*  stats  = (float*)(boff + 512);              // 128
    float*  scale  = stats + 128;                       // 64
    float*  shift  = scale + 64;                        // 64

    float2* binned = (float2*)hbuf;                     // scratch, consumed before gemm1

    float* out = (float*)d_out;

    const int SB = (SCAN_N + 255) / 256;   // 196
    const int ggrid = (NN + 63) / 64;      // 1563
    const int agrid = (NN + 7) / 8;        // 12500

    // ---------- CSR build: hist -> scan -> place -> bucket sort ----------
    hist_kernel<<<NCHUNKS, 256, 0, stream>>>(dst, counts);
    block_sums_kernel<<<SB, 256, 0, stream>>>(counts, bsums, SCAN_N);
    scan_bsums_kernel<<<1, 512, 0, stream>>>(bsums, boff, SB);
    scan_chunks_kernel<<<SB, 256, 0, stream>>>(counts, boff, gofs, SCAN_N);
    place_kernel<<<NCHUNKS, 256, 0, stream>>>(src, dst, ew, gofs, binned);
    bucket_sort_kernel<<<NBUCK, 256, 0, stream>>>(binned, gofs, edges, off);

    // ---------- layer 1: GCNConv(128->64) ----------
    gemm_mfma_kernel<128, 64, 4, false><<<ggrid, 256, 0, stream>>>(nf, W1, hbuf, NN, nullptr, nullptr);
    agg_kernel<64, false><<<agrid, 256, 0, stream>>>(hbuf, edges, off, aggbuf, nullptr);
    (void)hipMemsetAsync(stats, 0, 128 * sizeof(float), stream);
    bn_stats_kernel<<<512, 256, 0, stream>>>(aggbuf, stats, NN);
    bn_final_kernel<<<1, 64, 0, stream>>>(stats, g1, beta1, scale, shift);

    // ---------- layer 2: (BN+ReLU fused into GEMM load) GCNConv(64->64) ----------
    gemm_mfma_kernel<64, 64, 4, true><<<ggrid, 256, 0, stream>>>(aggbuf, W2, hbuf, NN, scale, shift);
    agg_kernel<64, false><<<agrid, 256, 0, stream>>>(hbuf, edges, off, aggbuf, nullptr);
    (void)hipMemsetAsync(stats, 0, 128 * sizeof(float), stream);
    bn_stats_kernel<<<512, 256, 0, stream>>>(aggbuf, stats, NN);
    bn_final_kernel<<<1, 64, 0, stream>>>(stats, g2, beta2, scale, shift);

    // ---------- layer 3: (BN+ReLU fused) GCNConv(64->40) + b3 ----------
    gemm_mfma_kernel<64, 40, 3, true><<<ggrid, 256, 0, stream>>>(aggbuf, W3, hbuf, NN, scale, shift);
    agg_kernel<40, true><<<agrid, 256, 0, stream>>>(hbuf, edges, off, out, b3);
}